// Round 13
// baseline (46.390 us; speedup 1.0000x reference)
//
#include <hip/hip_runtime.h>
#include <string.h>

// VectorQuantizer: N=65536 rows, K=1024 codes, D=16, fp32.
// Out layout (fp32): z_q_st [0,1048576) | loss [1048576] | indices-as-float [1048577,1114113)
// R13: R12's proven numerics; per-wave chain halved + occupancy doubled:
//   BLOCK=1024 (16 waves = 4 row-tiles x 4 k-quarters, TPW=8), NBLK=512,
//   __launch_bounds__(1024,8) -> VGPR<=64 -> 2 blocks/CU = 8 waves/SIMD.

typedef __bf16 bf16x8 __attribute__((ext_vector_type(8)));
typedef float  f32x16 __attribute__((ext_vector_type(16)));

constexpr int BLOCK = 1024;
constexpr int NROWS = 65536;
constexpr int K = 1024;
constexpr int RPB = 128;              // 4 row-tiles of 32 per block
constexpr int NBLK = NROWS / RPB;     // 512 blocks = 2/CU
constexpr int TPW = 8;                // k-tiles per wave (quarter of 32)
constexpr int CAP = 128;              // per-wave candidate capacity (E[cnt]~15)
constexpr float BAND = 1.5e-3f;       // proven R6/R8/R10/R12 (absmax 0)
constexpr int OFF_LOSS = 1048576;
constexpr int OFF_IDX  = 1048577;

// numpy pairwise_sum (n=16) of squares — bitwise matches np.sum(x**2, axis=1).
__device__ __forceinline__ float np_sumsq16(const float* a) {
  float s[16];
#pragma unroll
  for (int j = 0; j < 16; ++j) s[j] = __fmul_rn(a[j], a[j]);
  float r[8];
#pragma unroll
  for (int j = 0; j < 8; ++j) r[j] = __fadd_rn(s[j], s[j + 8]);
  const float t0 = __fadd_rn(r[0], r[1]);
  const float t1 = __fadd_rn(r[2], r[3]);
  const float t2 = __fadd_rn(r[4], r[5]);
  const float t3 = __fadd_rn(r[6], r[7]);
  return __fadd_rn(__fadd_rn(t0, t1), __fadd_rn(t2, t3));
}

// exact distance, identical rounding structure to R1..R12 (absmax 0 on this dataset)
__device__ __forceinline__ float np_dist(const float* zz, const float* ee,
                                         float z2, float e2k) {
  float c0 = zz[0]*ee[0];   c0 = fmaf(zz[1],ee[1],c0);   c0 = fmaf(zz[2],ee[2],c0);   c0 = fmaf(zz[3],ee[3],c0);
  float c1 = zz[4]*ee[4];   c1 = fmaf(zz[5],ee[5],c1);   c1 = fmaf(zz[6],ee[6],c1);   c1 = fmaf(zz[7],ee[7],c1);
  float c2 = zz[8]*ee[8];   c2 = fmaf(zz[9],ee[9],c2);   c2 = fmaf(zz[10],ee[10],c2); c2 = fmaf(zz[11],ee[11],c2);
  float c3 = zz[12]*ee[12]; c3 = fmaf(zz[13],ee[13],c3); c3 = fmaf(zz[14],ee[14],c3); c3 = fmaf(zz[15],ee[15],c3);
  const float dot = __fadd_rn(__fadd_rn(c0, c1), __fadd_rn(c2, c3));
  return __fmaf_rn(-2.0f, dot, __fadd_rn(z2, e2k));
}

// vq_pre: pack bf16 B-frags (tile tt, col c -> tt*1024 + c*16 (+512 hi)) + e2
__global__ __launch_bounds__(256)
void vq_pre(const float* __restrict__ emb, float* __restrict__ e2g,
            char* __restrict__ Bpack) {
  const int r = blockIdx.x * 256 + threadIdx.x;   // 4 blocks x 256 = 1024 codes
  const float4* g4 = reinterpret_cast<const float4*>(emb);
  float ee[16];
  float4* ev = reinterpret_cast<float4*>(ee);
#pragma unroll
  for (int j = 0; j < 4; ++j) ev[j] = g4[r * 4 + j];
  e2g[r] = np_sumsq16(ee);
  unsigned int wd[8];
#pragma unroll
  for (int j = 0; j < 8; ++j) {
    __bf16 lo = (__bf16)ee[2*j], hi = (__bf16)ee[2*j+1];   // RNE hw cvt
    unsigned short ulo, uhi;
    memcpy(&ulo, &lo, 2); memcpy(&uhi, &hi, 2);
    wd[j] = (unsigned int)ulo | ((unsigned int)uhi << 16);
  }
  const int tt = r >> 5, c = r & 31;
  *reinterpret_cast<uint4*>(Bpack + tt*1024 + c*16)       = make_uint4(wd[0], wd[1], wd[2], wd[3]);
  *reinterpret_cast<uint4*>(Bpack + tt*1024 + 512 + c*16) = make_uint4(wd[4], wd[5], wd[6], wd[7]);
}

__global__ __launch_bounds__(BLOCK, 8)   // cap VGPR at 64 -> 8 waves/SIMD with 2 blocks/CU
void vq_main(const float* __restrict__ z, const float* __restrict__ emb,
             const float* __restrict__ e2g, const char* __restrict__ Bpack,
             float* __restrict__ out, float* __restrict__ partials) {
  __shared__ unsigned int sclist[16][CAP];         // 8 KB candidates (row<<16|k)
  __shared__ unsigned long long smin64[4][32];     // 1 KB winner keys per row-tile
  __shared__ float smin[16][32];                   // 2 KB pass-A row mins per wave
  __shared__ int   scnt[16];
  __shared__ float sred[16];

  const int t = threadIdx.x;
  const int lane = t & 63;
  const int w = t >> 6;             // wave 0..15: row-tile (w>>2), k-quarter (w&3)
  const int rt = w >> 2;
  const int h = lane >> 5;
  const int rr = lane & 31;

  const float4* g4 = reinterpret_cast<const float4*>(emb);
  const float4* z4 = reinterpret_cast<const float4*>(z);

  if (lane == 0) scnt[w] = 0;
  if (t < 128) smin64[t >> 5][t & 31] = ~0ull;     // init all 4 row-tiles' winner keys

  // ---- A-frag: my row-tile's 32 z rows -> bf16 (lane: row rr, K-elems 8h..8h+7) ----
  const int wrow0 = blockIdx.x * RPB + rt * 32;
  const float* zrow = z + (size_t)(wrow0 + rr) * 16 + h * 8;
  const float4 a0 = *reinterpret_cast<const float4*>(zrow);
  const float4 a1 = *reinterpret_cast<const float4*>(zrow + 4);
  bf16x8 af;
  af[0]=(__bf16)a0.x; af[1]=(__bf16)a0.y; af[2]=(__bf16)a0.z; af[3]=(__bf16)a0.w;
  af[4]=(__bf16)a1.x; af[5]=(__bf16)a1.y; af[6]=(__bf16)a1.z; af[7]=(__bf16)a1.w;

  const int kt0 = (w & 3) * TPW;      // my k-quarter: tiles [kt0, kt0+TPW)
  const bf16x8* bfp = reinterpret_cast<const bf16x8*>(Bpack + (size_t)lane * 16);

  // ---- hoist pre = e2 + 0.5 for my 8 tiles (reused by both passes) ----
  float e2r[TPW];
#pragma unroll
  for (int j = 0; j < TPW; ++j) e2r[j] = e2g[(kt0 + j) * 32 + rr] + 0.5f;

  // ---- pass A: per-row approx min over my k-quarter ----
  float runm[16];
#pragma unroll
  for (int i = 0; i < 16; ++i) runm[i] = __builtin_inff();

#pragma unroll 4
  for (int tt = kt0; tt < kt0 + TPW; ++tt) {
    f32x16 zc = {};
    f32x16 acc = __builtin_amdgcn_mfma_f32_32x32x16_bf16(af, bfp[tt * 64], zc, 0, 0, 0);
    const float pre = e2r[tt - kt0];
#pragma unroll
    for (int i = 0; i < 16; ++i)
      runm[i] = fminf(runm[i], __fmaf_rn(-2.0f, acc[i], pre));
  }

  // cross-lane min over 32 cols (halves hold disjoint rows)
#pragma unroll
  for (int i = 0; i < 16; ++i)
#pragma unroll
    for (int m = 1; m < 32; m <<= 1)
      runm[i] = fminf(runm[i], __shfl_xor(runm[i], m));

  // ---- merge mins across the 4 k-quarters (physical-row indexed, order-indep) ----
  if (rr == 0) {
#pragma unroll
    for (int i = 0; i < 16; ++i)
      smin[w][(i & 3) + 8 * (i >> 2) + 4 * h] = runm[i];
  }
  __syncthreads();
#pragma unroll
  for (int i = 0; i < 16; ++i) {
    const int pr = (i & 3) + 8 * (i >> 2) + 4 * h;
    runm[i] = fminf(fminf(smin[rt*4+0][pr], smin[rt*4+1][pr]),
                    fminf(smin[rt*4+2][pr], smin[rt*4+3][pr])) + BAND;
  }

  // ---- pass B: recompute (bitwise-identical), per-lane atomic collect (proven) ----
#pragma unroll 4
  for (int tt = kt0; tt < kt0 + TPW; ++tt) {
    f32x16 zc = {};
    f32x16 acc = __builtin_amdgcn_mfma_f32_32x32x16_bf16(af, bfp[tt * 64], zc, 0, 0, 0);
    const float pre = e2r[tt - kt0];
    const int kcol = tt * 32 + rr;
#pragma unroll
    for (int i = 0; i < 16; ++i) {
      const float m = __fmaf_rn(-2.0f, acc[i], pre);
      if (m <= runm[i]) {
        const int rowloc = (i & 3) + 8 * (i >> 2) + 4 * h;
        const int slot = atomicAdd(&scnt[w], 1);
        if (slot < CAP) sclist[w][slot] = ((unsigned)rowloc << 16) | (unsigned)kcol;
      }
    }
  }
  int cnt = scnt[w]; if (cnt > CAP) cnt = CAP;   // own wave's LDS ops in issue order

  // ---- exact rescore (lane-parallel) + u64 atomicMin winner (order-independent;
  //      d>0 so float-bit order == numeric; ties -> smaller k == np first-index) ----
  for (int j0 = 0; j0 < cnt; j0 += 64) {
    const int j = j0 + lane;
    if (j < cnt) {
      const unsigned ent = sclist[w][j];
      const int rowj = (int)(ent >> 16), kj = (int)(ent & 1023);
      float zz[16]; float4* zv = reinterpret_cast<float4*>(zz);
#pragma unroll
      for (int q = 0; q < 4; ++q) zv[q] = z4[(size_t)(wrow0 + rowj) * 4 + q];
      float ee[16]; float4* ev = reinterpret_cast<float4*>(ee);
#pragma unroll
      for (int q = 0; q < 4; ++q) ev[q] = g4[(size_t)kj * 4 + q];
      const float d = np_dist(zz, ee, np_sumsq16(zz), e2g[kj]);
      const unsigned long long key =
          ((unsigned long long)__float_as_uint(d) << 32) | (unsigned long long)kj;
      atomicMin(&smin64[rt][rowj], key);
    }
  }
  __syncthreads();   // all waves' atomicMins done

  // ---- first wave of each row-tile: read winner per row, epilogue + loss partial ----
  float lsum = 0.0f;
  if ((w & 3) == 0 && lane < 32) {
    const int bk = (int)(smin64[rt][lane] & 1023ull);
    const int r = wrow0 + lane;
    float zz[16]; float4* zv = reinterpret_cast<float4*>(zz);
#pragma unroll
    for (int q = 0; q < 4; ++q) zv[q] = z4[(size_t)r * 4 + q];
    float ee[16]; float4* ev = reinterpret_cast<float4*>(ee);
#pragma unroll
    for (int q = 0; q < 4; ++q) ev[q] = g4[(size_t)bk * 4 + q];
    float ov[16];
#pragma unroll
    for (int j2 = 0; j2 < 16; ++j2) {
      const float d = __fsub_rn(ee[j2], zz[j2]);   // z_q - z
      lsum = fmaf(d, d, lsum);                     // loss partial
      ov[j2] = __fadd_rn(zz[j2], d);               // z + (z_q - z) == np z_q_st rounding
    }
    float4* o4 = reinterpret_cast<float4*>(out) + (size_t)r * 4;
    const float4* ovv = reinterpret_cast<const float4*>(ov);
#pragma unroll
    for (int q = 0; q < 4; ++q) o4[q] = ovv[q];
    out[OFF_IDX + r] = (float)bk;
  }

#pragma unroll
  for (int off = 32; off > 0; off >>= 1) lsum += __shfl_down(lsum, off);
  if (lane == 0) sred[w] = lsum;
  __syncthreads();
  if (t == 0) {
    float s = 0.0f;
#pragma unroll
    for (int j = 0; j < 16; ++j) s += sred[j];   // fixed order: deterministic
    partials[blockIdx.x] = s;
  }
}

__global__ __launch_bounds__(256)
void vq_fin(const float* __restrict__ partials, float* __restrict__ out) {
  const int t = threadIdx.x;
  float v = partials[t] + partials[t + 256];     // 512 partials, fixed order
#pragma unroll
  for (int off = 32; off > 0; off >>= 1) v += __shfl_down(v, off);
  __shared__ float s[4];
  if ((t & 63) == 0) s[t >> 6] = v;
  __syncthreads();
  if (t == 0) {
    const float S = (s[0] + s[1]) + (s[2] + s[3]);
    const float m = S / 1048576.0f;      // np.mean
    out[OFF_LOSS] = 1.25f * m;           // m + COMMITMENT_COST*m
  }
}

extern "C" void kernel_launch(void* const* d_in, const int* in_sizes, int n_in,
                              void* d_out, int out_size, void* d_ws, size_t ws_size,
                              hipStream_t stream) {
  const float* z   = reinterpret_cast<const float*>(d_in[0]);
  const float* emb = reinterpret_cast<const float*>(d_in[1]);
  float* out       = reinterpret_cast<float*>(d_out);
  float* e2g       = reinterpret_cast<float*>(d_ws);          // [0,1024) ||e_k||^2
  float* partials  = e2g + K;                                 // [1024,1536) 512 partials
  char*  Bpack     = reinterpret_cast<char*>(e2g + 2048);     // 32 KB bf16 frag table
  vq_pre <<<K / 256, 256, 0, stream>>>(emb, e2g, Bpack);
  vq_main<<<NBLK, BLOCK, 0, stream>>>(z, emb, e2g, Bpack, out, partials);
  vq_fin <<<1, 256, 0, stream>>>(partials, out);
}

// Round 14
// 42.462 us; speedup vs baseline: 1.0925x; 1.0925x over previous
//
#include <hip/hip_runtime.h>
#include <string.h>

// VectorQuantizer: N=65536 rows, K=1024 codes, D=16, fp32.
// Out layout (fp32): z_q_st [0,1048576) | loss [1048576] | indices-as-float [1048577,1114113)
// R14: R12 base (proven numerics), two stall fixes:
//   - __launch_bounds__(512,6): VGPR cap 85 (no spill; R13's cap-32 spilled), 6 waves/SIMD
//   - LOCAL pass-B threshold (own k-half min + BAND): sound superset, deletes the
//     cross-wave min merge and its barrier -> passes A+B run unsynchronized.

typedef __bf16 bf16x8 __attribute__((ext_vector_type(8)));
typedef float  f32x16 __attribute__((ext_vector_type(16)));

constexpr int BLOCK = 512;
constexpr int NROWS = 65536;
constexpr int K = 1024;
constexpr int RPB = 128;              // 4 row-tiles of 32 per block
constexpr int NBLK = NROWS / RPB;     // 512 blocks
constexpr int TPW = 16;               // k-tiles per wave (half of 32)
constexpr int CAP = 192;              // per-wave candidate capacity (E[cnt]~58 local-thr)
constexpr float BAND = 1.5e-3f;       // >= 2*bf16 error bound; absmax 0 since R6
constexpr int OFF_LOSS = 1048576;
constexpr int OFF_IDX  = 1048577;

// numpy pairwise_sum (n=16) of squares — bitwise matches np.sum(x**2, axis=1).
__device__ __forceinline__ float np_sumsq16(const float* a) {
  float s[16];
#pragma unroll
  for (int j = 0; j < 16; ++j) s[j] = __fmul_rn(a[j], a[j]);
  float r[8];
#pragma unroll
  for (int j = 0; j < 8; ++j) r[j] = __fadd_rn(s[j], s[j + 8]);
  const float t0 = __fadd_rn(r[0], r[1]);
  const float t1 = __fadd_rn(r[2], r[3]);
  const float t2 = __fadd_rn(r[4], r[5]);
  const float t3 = __fadd_rn(r[6], r[7]);
  return __fadd_rn(__fadd_rn(t0, t1), __fadd_rn(t2, t3));
}

// exact distance, identical rounding structure to R1..R12 (absmax 0 on this dataset)
__device__ __forceinline__ float np_dist(const float* zz, const float* ee,
                                         float z2, float e2k) {
  float c0 = zz[0]*ee[0];   c0 = fmaf(zz[1],ee[1],c0);   c0 = fmaf(zz[2],ee[2],c0);   c0 = fmaf(zz[3],ee[3],c0);
  float c1 = zz[4]*ee[4];   c1 = fmaf(zz[5],ee[5],c1);   c1 = fmaf(zz[6],ee[6],c1);   c1 = fmaf(zz[7],ee[7],c1);
  float c2 = zz[8]*ee[8];   c2 = fmaf(zz[9],ee[9],c2);   c2 = fmaf(zz[10],ee[10],c2); c2 = fmaf(zz[11],ee[11],c2);
  float c3 = zz[12]*ee[12]; c3 = fmaf(zz[13],ee[13],c3); c3 = fmaf(zz[14],ee[14],c3); c3 = fmaf(zz[15],ee[15],c3);
  const float dot = __fadd_rn(__fadd_rn(c0, c1), __fadd_rn(c2, c3));
  return __fmaf_rn(-2.0f, dot, __fadd_rn(z2, e2k));
}

// vq_pre: pack bf16 B-frags (tile tt, col c -> tt*1024 + c*16 (+512 hi)) + e2
__global__ __launch_bounds__(256)
void vq_pre(const float* __restrict__ emb, float* __restrict__ e2g,
            char* __restrict__ Bpack) {
  const int r = blockIdx.x * 256 + threadIdx.x;   // 4 blocks x 256 = 1024 codes
  const float4* g4 = reinterpret_cast<const float4*>(emb);
  float ee[16];
  float4* ev = reinterpret_cast<float4*>(ee);
#pragma unroll
  for (int j = 0; j < 4; ++j) ev[j] = g4[r * 4 + j];
  e2g[r] = np_sumsq16(ee);
  unsigned int wd[8];
#pragma unroll
  for (int j = 0; j < 8; ++j) {
    __bf16 lo = (__bf16)ee[2*j], hi = (__bf16)ee[2*j+1];   // RNE hw cvt
    unsigned short ulo, uhi;
    memcpy(&ulo, &lo, 2); memcpy(&uhi, &hi, 2);
    wd[j] = (unsigned int)ulo | ((unsigned int)uhi << 16);
  }
  const int tt = r >> 5, c = r & 31;
  *reinterpret_cast<uint4*>(Bpack + tt*1024 + c*16)       = make_uint4(wd[0], wd[1], wd[2], wd[3]);
  *reinterpret_cast<uint4*>(Bpack + tt*1024 + 512 + c*16) = make_uint4(wd[4], wd[5], wd[6], wd[7]);
}

__global__ __launch_bounds__(BLOCK, 6)   // VGPR cap 85 -> 3 blocks/CU = 6 waves/SIMD
void vq_main(const float* __restrict__ z, const float* __restrict__ emb,
             const float* __restrict__ e2g, const char* __restrict__ Bpack,
             float* __restrict__ out, float* __restrict__ partials) {
  __shared__ unsigned int sclist[8][CAP];          // 6 KB candidates (row<<16|k)
  __shared__ unsigned long long smin64[4][32];     // 1 KB winner keys per pair
  __shared__ int   scnt[8];
  __shared__ float sred[8];

  const int t = threadIdx.x;
  const int lane = t & 63;
  const int w = t >> 6;             // wave 0..7: pair (w>>1) owns a 32-row tile; (w&1)=k-half
  const int pair = w >> 1;
  const int h = lane >> 5;
  const int rr = lane & 31;

  const float4* g4 = reinterpret_cast<const float4*>(emb);
  const float4* z4 = reinterpret_cast<const float4*>(z);

  if (lane == 0) scnt[w] = 0;
  if (t < 128) smin64[t >> 5][t & 31] = ~0ull;     // init all 4 pairs' winner keys

  // ---- A-frag: my pair's 32 z rows -> bf16 (lane: row rr, K-elems 8h..8h+7) ----
  const int wrow0 = blockIdx.x * RPB + pair * 32;
  const float* zrow = z + (size_t)(wrow0 + rr) * 16 + h * 8;
  const float4 a0 = *reinterpret_cast<const float4*>(zrow);
  const float4 a1 = *reinterpret_cast<const float4*>(zrow + 4);
  bf16x8 af;
  af[0]=(__bf16)a0.x; af[1]=(__bf16)a0.y; af[2]=(__bf16)a0.z; af[3]=(__bf16)a0.w;
  af[4]=(__bf16)a1.x; af[5]=(__bf16)a1.y; af[6]=(__bf16)a1.z; af[7]=(__bf16)a1.w;

  const int kt0 = (w & 1) * TPW;      // my k-half: tiles [kt0, kt0+TPW)
  const bf16x8* bfp = reinterpret_cast<const bf16x8*>(Bpack + (size_t)lane * 16);

  // ---- hoist pre = e2 + 0.5 for my 16 tiles (reused by both passes) ----
  float e2r[TPW];
#pragma unroll
  for (int j = 0; j < TPW; ++j) e2r[j] = e2g[(kt0 + j) * 32 + rr] + 0.5f;

  // ---- pass A: per-row approx min over my k-half ----
  float runm[16];
#pragma unroll
  for (int i = 0; i < 16; ++i) runm[i] = __builtin_inff();

#pragma unroll 4
  for (int tt = kt0; tt < kt0 + TPW; ++tt) {
    f32x16 zc = {};
    f32x16 acc = __builtin_amdgcn_mfma_f32_32x32x16_bf16(af, bfp[tt * 64], zc, 0, 0, 0);
    const float pre = e2r[tt - kt0];
#pragma unroll
    for (int i = 0; i < 16; ++i)
      runm[i] = fminf(runm[i], __fmaf_rn(-2.0f, acc[i], pre));
  }

  // cross-lane min over 32 cols (halves hold disjoint rows); LOCAL threshold:
  // any exact-argmin k* in my half satisfies m_k* <= my_min + 2E <= my_min + BAND.
#pragma unroll
  for (int i = 0; i < 16; ++i) {
#pragma unroll
    for (int m = 1; m < 32; m <<= 1)
      runm[i] = fminf(runm[i], __shfl_xor(runm[i], m));
    runm[i] += BAND;
  }

  // ---- pass B: recompute (bitwise-identical), per-lane atomic collect (proven) ----
  // NO barrier since pass A: threshold is wave-local.
#pragma unroll 4
  for (int tt = kt0; tt < kt0 + TPW; ++tt) {
    f32x16 zc = {};
    f32x16 acc = __builtin_amdgcn_mfma_f32_32x32x16_bf16(af, bfp[tt * 64], zc, 0, 0, 0);
    const float pre = e2r[tt - kt0];
    const int kcol = tt * 32 + rr;
#pragma unroll
    for (int i = 0; i < 16; ++i) {
      const float m = __fmaf_rn(-2.0f, acc[i], pre);
      if (m <= runm[i]) {
        const int rowloc = (i & 3) + 8 * (i >> 2) + 4 * h;
        const int slot = atomicAdd(&scnt[w], 1);
        if (slot < CAP) sclist[w][slot] = ((unsigned)rowloc << 16) | (unsigned)kcol;
      }
    }
  }
  int cnt = scnt[w]; if (cnt > CAP) cnt = CAP;   // own wave's LDS ops in issue order

  __syncthreads();   // smin64 init (top) complete before any atomicMin below

  // ---- exact rescore (lane-parallel) + u64 atomicMin winner (order-independent;
  //      d>0 so float-bit order == numeric; ties -> smaller k == np first-index) ----
  for (int j0 = 0; j0 < cnt; j0 += 64) {
    const int j = j0 + lane;
    if (j < cnt) {
      const unsigned ent = sclist[w][j];
      const int rowj = (int)(ent >> 16), kj = (int)(ent & 1023);
      float zz[16]; float4* zv = reinterpret_cast<float4*>(zz);
#pragma unroll
      for (int q = 0; q < 4; ++q) zv[q] = z4[(size_t)(wrow0 + rowj) * 4 + q];
      float ee[16]; float4* ev = reinterpret_cast<float4*>(ee);
#pragma unroll
      for (int q = 0; q < 4; ++q) ev[q] = g4[(size_t)kj * 4 + q];
      const float d = np_dist(zz, ee, np_sumsq16(zz), e2g[kj]);
      const unsigned long long key =
          ((unsigned long long)__float_as_uint(d) << 32) | (unsigned long long)kj;
      atomicMin(&smin64[pair][rowj], key);
    }
  }
  __syncthreads();   // all pairs' atomicMins done

  // ---- even wave of each pair: read winner per row, epilogue + loss partial ----
  float lsum = 0.0f;
  if (!(w & 1) && lane < 32) {
    const int bk = (int)(smin64[pair][lane] & 1023ull);
    const int r = wrow0 + lane;
    float zz[16]; float4* zv = reinterpret_cast<float4*>(zz);
#pragma unroll
    for (int q = 0; q < 4; ++q) zv[q] = z4[(size_t)r * 4 + q];
    float ee[16]; float4* ev = reinterpret_cast<float4*>(ee);
#pragma unroll
    for (int q = 0; q < 4; ++q) ev[q] = g4[(size_t)bk * 4 + q];
    float ov[16];
#pragma unroll
    for (int j2 = 0; j2 < 16; ++j2) {
      const float d = __fsub_rn(ee[j2], zz[j2]);   // z_q - z
      lsum = fmaf(d, d, lsum);                     // loss partial
      ov[j2] = __fadd_rn(zz[j2], d);               // z + (z_q - z) == np z_q_st rounding
    }
    float4* o4 = reinterpret_cast<float4*>(out) + (size_t)r * 4;
    const float4* ovv = reinterpret_cast<const float4*>(ov);
#pragma unroll
    for (int q = 0; q < 4; ++q) o4[q] = ovv[q];
    out[OFF_IDX + r] = (float)bk;
  }

#pragma unroll
  for (int off = 32; off > 0; off >>= 1) lsum += __shfl_down(lsum, off);
  if (lane == 0) sred[w] = lsum;
  __syncthreads();
  if (t == 0)
    partials[blockIdx.x] = ((sred[0] + sred[1]) + (sred[2] + sred[3]))
                         + ((sred[4] + sred[5]) + (sred[6] + sred[7]));
}

__global__ __launch_bounds__(256)
void vq_fin(const float* __restrict__ partials, float* __restrict__ out) {
  const int t = threadIdx.x;
  float v = partials[t] + partials[t + 256];     // 512 partials, fixed order
#pragma unroll
  for (int off = 32; off > 0; off >>= 1) v += __shfl_down(v, off);
  __shared__ float s[4];
  if ((t & 63) == 0) s[t >> 6] = v;
  __syncthreads();
  if (t == 0) {
    const float S = (s[0] + s[1]) + (s[2] + s[3]);
    const float m = S / 1048576.0f;      // np.mean
    out[OFF_LOSS] = 1.25f * m;           // m + COMMITMENT_COST*m
  }
}

extern "C" void kernel_launch(void* const* d_in, const int* in_sizes, int n_in,
                              void* d_out, int out_size, void* d_ws, size_t ws_size,
                              hipStream_t stream) {
  const float* z   = reinterpret_cast<const float*>(d_in[0]);
  const float* emb = reinterpret_cast<const float*>(d_in[1]);
  float* out       = reinterpret_cast<float*>(d_out);
  float* e2g       = reinterpret_cast<float*>(d_ws);          // [0,1024) ||e_k||^2
  float* partials  = e2g + K;                                 // [1024,1536) 512 partials
  char*  Bpack     = reinterpret_cast<char*>(e2g + 2048);     // 32 KB bf16 frag table
  vq_pre <<<K / 256, 256, 0, stream>>>(emb, e2g, Bpack);
  vq_main<<<NBLK, BLOCK, 0, stream>>>(z, emb, e2g, Bpack, out, partials);
  vq_fin <<<1, 256, 0, stream>>>(partials, out);
}

// Round 15
// 37.369 us; speedup vs baseline: 1.2414x; 1.1363x over previous
//
#include <hip/hip_runtime.h>
#include <string.h>

// VectorQuantizer: N=65536 rows, K=1024 codes, D=16, fp32.
// Out layout (fp32): z_q_st [0,1048576) | loss [1048576] | indices-as-float [1048577,1114113)
// R15: R12's proven compute, 2 dispatches instead of 3:
//   - vq_pre ELIMINATED: B-frags converted on the fly from emb (same RNE cvt -> same bits),
//     e2 table built in block LDS (same np_sumsq16 -> same bits)
//   - everything else identical to R12 (pair k-split, BAND, atomic collect,
//     u64-atomicMin winner, np-bitwise rescore/epilogue, vq_fin)

typedef __bf16 bf16x8 __attribute__((ext_vector_type(8)));
typedef float  f32x16 __attribute__((ext_vector_type(16)));

constexpr int BLOCK = 512;
constexpr int NROWS = 65536;
constexpr int K = 1024;
constexpr int RPB = 128;              // 4 row-tiles of 32 per block
constexpr int NBLK = NROWS / RPB;     // 512 blocks = 2/CU
constexpr int TPW = 16;               // k-tiles per wave (half of 32)
constexpr int CAP = 192;              // per-wave candidate capacity (E[cnt]~29)
constexpr float BAND = 1.5e-3f;       // proven R6..R12 (absmax 0)
constexpr int OFF_LOSS = 1048576;
constexpr int OFF_IDX  = 1048577;

// numpy pairwise_sum (n=16) of squares — bitwise matches np.sum(x**2, axis=1).
__device__ __forceinline__ float np_sumsq16(const float* a) {
  float s[16];
#pragma unroll
  for (int j = 0; j < 16; ++j) s[j] = __fmul_rn(a[j], a[j]);
  float r[8];
#pragma unroll
  for (int j = 0; j < 8; ++j) r[j] = __fadd_rn(s[j], s[j + 8]);
  const float t0 = __fadd_rn(r[0], r[1]);
  const float t1 = __fadd_rn(r[2], r[3]);
  const float t2 = __fadd_rn(r[4], r[5]);
  const float t3 = __fadd_rn(r[6], r[7]);
  return __fadd_rn(__fadd_rn(t0, t1), __fadd_rn(t2, t3));
}

// exact distance, identical rounding structure to R1..R12 (absmax 0 on this dataset)
__device__ __forceinline__ float np_dist(const float* zz, const float* ee,
                                         float z2, float e2k) {
  float c0 = zz[0]*ee[0];   c0 = fmaf(zz[1],ee[1],c0);   c0 = fmaf(zz[2],ee[2],c0);   c0 = fmaf(zz[3],ee[3],c0);
  float c1 = zz[4]*ee[4];   c1 = fmaf(zz[5],ee[5],c1);   c1 = fmaf(zz[6],ee[6],c1);   c1 = fmaf(zz[7],ee[7],c1);
  float c2 = zz[8]*ee[8];   c2 = fmaf(zz[9],ee[9],c2);   c2 = fmaf(zz[10],ee[10],c2); c2 = fmaf(zz[11],ee[11],c2);
  float c3 = zz[12]*ee[12]; c3 = fmaf(zz[13],ee[13],c3); c3 = fmaf(zz[14],ee[14],c3); c3 = fmaf(zz[15],ee[15],c3);
  const float dot = __fadd_rn(__fadd_rn(c0, c1), __fadd_rn(c2, c3));
  return __fmaf_rn(-2.0f, dot, __fadd_rn(z2, e2k));
}

// on-the-fly B-frag: lane (h,rr) of tile tt loads emb[tt*32+rr][8h..8h+7], casts bf16 (RNE)
__device__ __forceinline__ bf16x8 load_bfrag(const float4* g4, int tt, int rr, int h) {
  const float4 b0 = g4[(tt * 32 + rr) * 4 + 2 * h];
  const float4 b1 = g4[(tt * 32 + rr) * 4 + 2 * h + 1];
  bf16x8 bf;
  bf[0]=(__bf16)b0.x; bf[1]=(__bf16)b0.y; bf[2]=(__bf16)b0.z; bf[3]=(__bf16)b0.w;
  bf[4]=(__bf16)b1.x; bf[5]=(__bf16)b1.y; bf[6]=(__bf16)b1.z; bf[7]=(__bf16)b1.w;
  return bf;
}

__global__ __launch_bounds__(BLOCK, 4)   // 8 waves/block, 2 blocks/CU -> 4 waves/SIMD
void vq_main(const float* __restrict__ z, const float* __restrict__ emb,
             float* __restrict__ out, float* __restrict__ partials) {
  __shared__ float se2[K];                         // 4 KB np-bitwise ||e_k||^2
  __shared__ unsigned int sclist[8][CAP];          // 6 KB candidates (row<<16|k)
  __shared__ unsigned long long smin64[4][32];     // 1 KB winner keys per pair
  __shared__ float smin[8][32];                    // 1 KB pass-A row mins per wave
  __shared__ int   scnt[8];
  __shared__ float sred[8];

  const int t = threadIdx.x;
  const int lane = t & 63;
  const int w = t >> 6;             // wave 0..7: pair (w>>1) owns a 32-row tile; (w&1)=k-half
  const int pair = w >> 1;
  const int h = lane >> 5;
  const int rr = lane & 31;

  const float4* g4 = reinterpret_cast<const float4*>(emb);
  const float4* z4 = reinterpret_cast<const float4*>(z);

  if (lane == 0) scnt[w] = 0;
  if (t < 128) smin64[t >> 5][t & 31] = ~0ull;     // init all 4 pairs' winner keys

  // ---- block-level e2 table (replaces vq_pre's e2g): 2 codes per thread ----
#pragma unroll
  for (int n = 0; n < 2; ++n) {
    const int c = t + n * BLOCK;
    float ee[16];
    float4* ev = reinterpret_cast<float4*>(ee);
#pragma unroll
    for (int j = 0; j < 4; ++j) ev[j] = g4[c * 4 + j];
    se2[c] = np_sumsq16(ee);
  }

  // ---- A-frag: my pair's 32 z rows -> bf16 (lane: row rr, K-elems 8h..8h+7) ----
  const int wrow0 = blockIdx.x * RPB + pair * 32;
  const float* zrow = z + (size_t)(wrow0 + rr) * 16 + h * 8;
  const float4 a0 = *reinterpret_cast<const float4*>(zrow);
  const float4 a1 = *reinterpret_cast<const float4*>(zrow + 4);
  bf16x8 af;
  af[0]=(__bf16)a0.x; af[1]=(__bf16)a0.y; af[2]=(__bf16)a0.z; af[3]=(__bf16)a0.w;
  af[4]=(__bf16)a1.x; af[5]=(__bf16)a1.y; af[6]=(__bf16)a1.z; af[7]=(__bf16)a1.w;

  const int kt0 = (w & 1) * TPW;      // my k-half: tiles [kt0, kt0+TPW)

  __syncthreads();                    // se2 complete

  // ---- hoist pre = e2 + 0.5 for my 16 tiles (broadcast ds_reads, both passes) ----
  float e2r[TPW];
#pragma unroll
  for (int j = 0; j < TPW; ++j) e2r[j] = se2[(kt0 + j) * 32 + rr] + 0.5f;

  // ---- pass A: per-row approx min over my k-half ----
  float runm[16];
#pragma unroll
  for (int i = 0; i < 16; ++i) runm[i] = __builtin_inff();

#pragma unroll 4
  for (int tt = kt0; tt < kt0 + TPW; ++tt) {
    f32x16 zc = {};
    f32x16 acc = __builtin_amdgcn_mfma_f32_32x32x16_bf16(af, load_bfrag(g4, tt, rr, h), zc, 0, 0, 0);
    const float pre = e2r[tt - kt0];
#pragma unroll
    for (int i = 0; i < 16; ++i)
      runm[i] = fminf(runm[i], __fmaf_rn(-2.0f, acc[i], pre));
  }

  // cross-lane min over 32 cols (halves hold disjoint rows)
#pragma unroll
  for (int i = 0; i < 16; ++i)
#pragma unroll
    for (int m = 1; m < 32; m <<= 1)
      runm[i] = fminf(runm[i], __shfl_xor(runm[i], m));

  // ---- merge mins across the k-half pair (physical-row indexed) ----
  if (rr == 0) {
#pragma unroll
    for (int i = 0; i < 16; ++i)
      smin[w][(i & 3) + 8 * (i >> 2) + 4 * h] = runm[i];
  }
  __syncthreads();
#pragma unroll
  for (int i = 0; i < 16; ++i)
    runm[i] = fminf(runm[i], smin[w ^ 1][(i & 3) + 8 * (i >> 2) + 4 * h]) + BAND;

  // ---- pass B: recompute (bitwise-identical), per-lane atomic collect (proven) ----
#pragma unroll 4
  for (int tt = kt0; tt < kt0 + TPW; ++tt) {
    f32x16 zc = {};
    f32x16 acc = __builtin_amdgcn_mfma_f32_32x32x16_bf16(af, load_bfrag(g4, tt, rr, h), zc, 0, 0, 0);
    const float pre = e2r[tt - kt0];
    const int kcol = tt * 32 + rr;
#pragma unroll
    for (int i = 0; i < 16; ++i) {
      const float m = __fmaf_rn(-2.0f, acc[i], pre);
      if (m <= runm[i]) {
        const int rowloc = (i & 3) + 8 * (i >> 2) + 4 * h;
        const int slot = atomicAdd(&scnt[w], 1);
        if (slot < CAP) sclist[w][slot] = ((unsigned)rowloc << 16) | (unsigned)kcol;
      }
    }
  }
  int cnt = scnt[w]; if (cnt > CAP) cnt = CAP;   // own wave's LDS ops in issue order

  // ---- exact rescore (lane-parallel) + u64 atomicMin winner (order-independent;
  //      d>0 so float-bit order == numeric; ties -> smaller k == np first-index) ----
  for (int j0 = 0; j0 < cnt; j0 += 64) {
    const int j = j0 + lane;
    if (j < cnt) {
      const unsigned ent = sclist[w][j];
      const int rowj = (int)(ent >> 16), kj = (int)(ent & 1023);
      float zz[16]; float4* zv = reinterpret_cast<float4*>(zz);
#pragma unroll
      for (int q = 0; q < 4; ++q) zv[q] = z4[(size_t)(wrow0 + rowj) * 4 + q];
      float ee[16]; float4* ev = reinterpret_cast<float4*>(ee);
#pragma unroll
      for (int q = 0; q < 4; ++q) ev[q] = g4[(size_t)kj * 4 + q];
      const float d = np_dist(zz, ee, np_sumsq16(zz), se2[kj]);
      const unsigned long long key =
          ((unsigned long long)__float_as_uint(d) << 32) | (unsigned long long)kj;
      atomicMin(&smin64[pair][rowj], key);
    }
  }
  __syncthreads();   // all pairs' atomicMins done

  // ---- even wave of each pair: read winner per row, epilogue + loss partial ----
  float lsum = 0.0f;
  if (!(w & 1) && lane < 32) {
    const int bk = (int)(smin64[pair][lane] & 1023ull);
    const int r = wrow0 + lane;
    float zz[16]; float4* zv = reinterpret_cast<float4*>(zz);
#pragma unroll
    for (int q = 0; q < 4; ++q) zv[q] = z4[(size_t)r * 4 + q];
    float ee[16]; float4* ev = reinterpret_cast<float4*>(ee);
#pragma unroll
    for (int q = 0; q < 4; ++q) ev[q] = g4[(size_t)bk * 4 + q];
    float ov[16];
#pragma unroll
    for (int j2 = 0; j2 < 16; ++j2) {
      const float d = __fsub_rn(ee[j2], zz[j2]);   // z_q - z
      lsum = fmaf(d, d, lsum);                     // loss partial
      ov[j2] = __fadd_rn(zz[j2], d);               // z + (z_q - z) == np z_q_st rounding
    }
    float4* o4 = reinterpret_cast<float4*>(out) + (size_t)r * 4;
    const float4* ovv = reinterpret_cast<const float4*>(ov);
#pragma unroll
    for (int q = 0; q < 4; ++q) o4[q] = ovv[q];
    out[OFF_IDX + r] = (float)bk;
  }

#pragma unroll
  for (int off = 32; off > 0; off >>= 1) lsum += __shfl_down(lsum, off);
  if (lane == 0) sred[w] = lsum;
  __syncthreads();
  if (t == 0)
    partials[blockIdx.x] = ((sred[0] + sred[1]) + (sred[2] + sred[3]))
                         + ((sred[4] + sred[5]) + (sred[6] + sred[7]));
}

__global__ __launch_bounds__(256)
void vq_fin(const float* __restrict__ partials, float* __restrict__ out) {
  const int t = threadIdx.x;
  float v = partials[t] + partials[t + 256];     // 512 partials, fixed order
#pragma unroll
  for (int off = 32; off > 0; off >>= 1) v += __shfl_down(v, off);
  __shared__ float s[4];
  if ((t & 63) == 0) s[t >> 6] = v;
  __syncthreads();
  if (t == 0) {
    const float S = (s[0] + s[1]) + (s[2] + s[3]);
    const float m = S / 1048576.0f;      // np.mean
    out[OFF_LOSS] = 1.25f * m;           // m + COMMITMENT_COST*m
  }
}

extern "C" void kernel_launch(void* const* d_in, const int* in_sizes, int n_in,
                              void* d_out, int out_size, void* d_ws, size_t ws_size,
                              hipStream_t stream) {
  const float* z   = reinterpret_cast<const float*>(d_in[0]);
  const float* emb = reinterpret_cast<const float*>(d_in[1]);
  float* out       = reinterpret_cast<float*>(d_out);
  float* partials  = reinterpret_cast<float*>(d_ws);   // 512 floats scratch
  vq_main<<<NBLK, BLOCK, 0, stream>>>(z, emb, out, partials);
  vq_fin <<<1, 256, 0, stream>>>(partials, out);
}